// Round 13
// baseline (111.071 us; speedup 1.0000x reference)
//
#include <hip/hip_runtime.h>
#include <stdint.h>
#include <string.h>
#include <algorithm>

#define NV 4096
#define NPOOL 1024
#define NB 8
#define KNB 16
#define REMOVED 0xFFFFFFFFu
#define CANDCAP 128
// bank-deconflicted histogram index: bin b -> word (b>>4) | ((b&15)<<6)
#define HIDX(b) ((((b) >> 4) | (((b) & 15) << 6)))

struct SIdx { unsigned short v[NPOOL]; };  // 2 KB by-value kernel arg

// ---------------- Threefry-2x32 (JAX-compatible, 20 rounds), host ----------
static inline void tf2x32_host(uint32_t k0, uint32_t k1,
                               uint32_t c0, uint32_t c1,
                               uint32_t& o0, uint32_t& o1) {
  uint32_t ks0 = k0, ks1 = k1, ks2 = k0 ^ k1 ^ 0x1BD11BDAu;
  uint32_t x0 = c0 + ks0, x1 = c1 + ks1;
#define TFR(r) { x0 += x1; x1 = (x1 << (r)) | (x1 >> (32 - (r))); x1 ^= x0; }
  TFR(13) TFR(15) TFR(26) TFR(6)
  x0 += ks1; x1 += ks2 + 1u;
  TFR(17) TFR(29) TFR(16) TFR(24)
  x0 += ks2; x1 += ks0 + 2u;
  TFR(13) TFR(15) TFR(26) TFR(6)
  x0 += ks0; x1 += ks1 + 3u;
  TFR(17) TFR(29) TFR(16) TFR(24)
  x0 += ks1; x1 += ks2 + 4u;
  TFR(13) TFR(15) TFR(26) TFR(6)
  x0 += ks2; x1 += ks0 + 5u;
#undef TFR
  o0 = x0; o1 = x1;
}

// Host: replicate jax.random.permutation(key(42), 4096)[:1024]  (validated absmax=0)
static void compute_sample_idx(SIdx& out) {
  static_assert(sizeof(SIdx) == 2048, "kernarg size");
  uint64_t arr[NV];
  uint16_t x[NV], tmp[NV];
  for (int i = 0; i < NV; ++i) x[i] = (uint16_t)i;
  uint32_t kh = 0u, kl = 42u;
  for (int round = 0; round < 2; ++round) {
    uint32_t nkh, nkl, sh, sl, t0, t1;
    tf2x32_host(kh, kl, 0u, 0u, nkh, nkl);
    tf2x32_host(kh, kl, 0u, 1u, sh, sl);
    kh = nkh; kl = nkl;
    for (int i = 0; i < NV; ++i) {
      tf2x32_host(sh, sl, 0u, (uint32_t)i, t0, t1);
      arr[i] = ((uint64_t)(t0 ^ t1) << 32) | (uint32_t)i;
    }
    std::sort(arr, arr + NV);
    for (int i = 0; i < NV; ++i) tmp[i] = x[(uint32_t)(arr[i] & 0xffffffffu)];
    memcpy(x, tmp, sizeof(x));
  }
  for (int i = 0; i < NPOOL; ++i) out.v[i] = x[i];
}

// 4 distances of group g (verts lane*64+4g .. +3), validated XLA arithmetic;
// self -> REMOVED. vb4 = lane's vertex base as float4*.
__device__ __forceinline__ void dist4(const float4* __restrict__ vb4, int g,
                                      float qx, float qy, float qz, float qn,
                                      int selfT, uint32_t dv[4]) {
  const float4 A = vb4[g * 3 + 0];
  const float4 B = vb4[g * 3 + 1];
  const float4 Cc = vb4[g * 3 + 2];
  const float xs[12] = {A.x, A.y, A.z, A.w, B.x, B.y, B.z, B.w,
                        Cc.x, Cc.y, Cc.z, Cc.w};
#pragma unroll
  for (int k = 0; k < 4; ++k) {
    const float cx = xs[3 * k + 0], cy = xs[3 * k + 1], cz = xs[3 * k + 2];
    const float inner = __fmaf_rn(cz, qz, __fmaf_rn(cy, qy, __fmul_rn(cx, qx)));
    const float qm = __fadd_rn(__fadd_rn(__fmul_rn(cx, cx), __fmul_rn(cy, cy)),
                               __fmul_rn(cz, cz));
    const float ds = __fadd_rn(__fadd_rn(__fmul_rn(-2.0f, inner), qm), qn);
    dv[k] = ((g * 4 + k) == selfT) ? REMOVED : __float_as_uint(ds);
  }
}

// ---------------- K1: one query per 64-thread (single-wave) block.
// Two-pass: (1) running lane-min -> minima histogram -> threshold bin taub;
// (2) recompute (bit-identical) + append bin<=taub -> rank-select top-16.
// No idle-lane phases; barriers are single-wave (near-free).
__global__ __launch_bounds__(64) void knn_pool_kernel(
    const float* __restrict__ vertices, const float* __restrict__ fm,
    const SIdx sidx,
    float* __restrict__ outV, float* __restrict__ outF) {
  __shared__ uint32_t hist[1024];
  __shared__ unsigned long long cand[CANDCAP];
  __shared__ int winners[KNB];
  __shared__ int s_nc, s_tb;

  const int lane = threadIdx.x;
  const int blk = blockIdx.x;      // 0..8191
  const int b = blk & 7;           // XCD-aware: batch b -> XCD b (bijective)
  const int i = blk >> 3;
  const int n = (int)sidx.v[i];

  const float* vb = vertices + (size_t)b * NV * 3;
  const float qx = vb[n * 3 + 0], qy = vb[n * 3 + 1], qz = vb[n * 3 + 2];
  // quadratic[n]: plain mul/add (XLA reduce of squares) — validated arithmetic
  const float qn = __fadd_rn(__fadd_rn(__fmul_rn(qx, qx), __fmul_rn(qy, qy)),
                             __fmul_rn(qz, qz));

  const int selfT = ((n >> 6) == lane) ? (n & 63) : -1;
  const float4* vb4 = (const float4*)vb + lane * 48;  // 64 verts, 768 B

  // zero hist (1024 words = 256 uint4 over 64 lanes)
  {
    const uint4 z4 = make_uint4(0, 0, 0, 0);
    uint4* h4 = (uint4*)hist;
    h4[lane] = z4; h4[lane + 64] = z4; h4[lane + 128] = z4; h4[lane + 192] = z4;
  }
  if (lane == 0) s_nc = 0;

  // pass 1: running min over this lane's 64 candidates (no d[] storage)
  uint32_t mn = REMOVED;
#pragma unroll 4
  for (int g = 0; g < 16; ++g) {
    uint32_t dv[4];
    dist4(vb4, g, qx, qy, qz, qn, selfT, dv);
#pragma unroll
    for (int k = 0; k < 4; ++k) mn = (dv[k] < mn) ? dv[k] : mn;
  }
  __syncthreads();

  // minima histogram: 64 atomics
  atomicAdd(&hist[HIDX(mn >> 22)], 1u);
  __syncthreads();

  // scan: crossing bin taub where cumulative minima-count reaches KNB.
  // Validity: any true top-16 value has bin <= taub (else >=16 strictly
  // smaller lane-minima exist — contradiction).
  {
    uint32_t s = 0;
#pragma unroll
    for (int j = 0; j < 16; ++j) s += hist[j * 64 + lane];  // HIDX(lane*16+j)
    uint32_t inc = s;
    for (int off = 1; off < 64; off <<= 1) {
      const uint32_t o = (uint32_t)__shfl_up((int)inc, off);
      if (lane >= off) inc += o;
    }
    const uint32_t pre = inc - s;
    const bool cross = (pre < KNB) && (inc >= KNB);
    const unsigned long long bal = __ballot(cross);
    const int leader = __ffsll((unsigned long long)bal) - 1;
    if (lane == leader) {
      uint32_t c = pre;
      int tb = lane * 16 + 15;
      for (int j = 0; j < 16; ++j) {
        const uint32_t h = hist[j * 64 + lane];
        if (c + h >= KNB) { tb = lane * 16 + j; break; }
        c += h;
      }
      s_tb = tb;
    }
  }
  __syncthreads();
  const uint32_t taub = (uint32_t)s_tb;

  // pass 2: recompute (bit-identical) + append candidates with bin <= taub
#pragma unroll 4
  for (int g = 0; g < 16; ++g) {
    uint32_t dv[4];
    dist4(vb4, g, qx, qy, qz, qn, selfT, dv);
#pragma unroll
    for (int k = 0; k < 4; ++k) {
      const uint32_t v = dv[k];
      if ((v >> 22) <= taub) {
        const int s = atomicAdd(&s_nc, 1);
        if (s < CANDCAP)
          cand[s] = ((unsigned long long)v << 32) |
                    (uint32_t)((lane << 6) + g * 4 + k);
      }
    }
  }
  __syncthreads();

  const int C = s_nc;
  if (C <= CANDCAP) {
    // dual-entry per-lane rank selection (exact top-16 by (dist,idx) u64 order)
    const unsigned long long me0 =
        (lane < C) ? cand[lane] : 0xFFFFFFFFFFFFFFFFull;
    const unsigned long long me1 =
        (lane + 64 < C) ? cand[lane + 64] : 0xFFFFFFFFFFFFFFFFull;
    int r0 = 0, r1 = 0;
    for (int j = 0; j < C; ++j) {          // cand[j]: LDS broadcast read
      const unsigned long long cj = cand[j];
      r0 += (cj < me0) ? 1 : 0;
      r1 += (cj < me1) ? 1 : 0;
    }
    if (lane < C && r0 < KNB) winners[r0] = (int)(me0 & 0xFFFFFFFFu);
    if (lane + 64 < C && r1 < KNB) winners[r1] = (int)(me1 & 0xFFFFFFFFu);
    __syncthreads();
  } else {
    // rare fallback: 16-round extraction, recompute per round (wave-local)
    unsigned long long mask = 0ull;
    for (int r = 0; r < KNB; ++r) {
      uint32_t bv = REMOVED, bm = 0xFFFFFFFFu;
#pragma unroll 2
      for (int g = 0; g < 16; ++g) {
        uint32_t dv[4];
        dist4(vb4, g, qx, qy, qz, qn, selfT, dv);
#pragma unroll
        for (int k = 0; k < 4; ++k) {
          const int t = g * 4 + k;
          uint32_t v = dv[k];
          if (((mask >> t) & 1ull) || ((v >> 22) > taub)) v = REMOVED;
          const uint32_t m = (uint32_t)((lane << 6) + t);
          if (v < bv || (v == bv && m < bm)) { bv = v; bm = m; }
        }
      }
      for (int off = 32; off > 0; off >>= 1) {
        const uint32_t ov = (uint32_t)__shfl_down((int)bv, off);
        const uint32_t om = (uint32_t)__shfl_down((int)bm, off);
        if (ov < bv || (ov == bv && om < bm)) { bv = ov; bm = om; }
      }
      const int w = __shfl((int)bm, 0);
      if (lane == 0) winners[r] = w;
      if (lane == (w >> 6)) mask |= 1ull << (w & 63);
    }
    __syncthreads();
  }

  // fused gather + max over the winner set (order-invariant), float4 rows
  const float* fmb = fm + (size_t)b * NV * 256;
  float4 acc = make_float4(-INFINITY, -INFINITY, -INFINITY, -INFINITY);
#pragma unroll
  for (int s2 = 0; s2 < KNB; ++s2) {
    const int w = winners[s2];
    const float4 v = ((const float4*)(fmb + (size_t)w * 256))[lane];
    acc.x = fmaxf(acc.x, v.x); acc.y = fmaxf(acc.y, v.y);
    acc.z = fmaxf(acc.z, v.z); acc.w = fmaxf(acc.w, v.w);
  }
  ((float4*)(outF + ((size_t)b * NPOOL + i) * 256))[lane] = acc;
  if (lane < 3) outV[((size_t)b * NPOOL + i) * 3 + lane] = vb[n * 3 + lane];
}

extern "C" void kernel_launch(void* const* d_in, const int* in_sizes, int n_in,
                              void* d_out, int out_size, void* d_ws, size_t ws_size,
                              hipStream_t stream) {
  const float* vertices = (const float*)d_in[0];
  const float* fm = (const float*)d_in[1];
  float* out = (float*)d_out;
  float* outV = out;                      // (8, 1024, 3)
  float* outF = out + NB * NPOOL * 3;     // (8, 1024, 256)

  SIdx sidx;
  compute_sample_idx(sidx);               // pure host constant of key(42)

  knn_pool_kernel<<<NB * NPOOL, 64, 0, stream>>>(vertices, fm, sidx, outV, outF);
}

// Round 14
// 36.985 us; speedup vs baseline: 3.0031x; 3.0031x over previous
//
#include <hip/hip_runtime.h>
#include <stdint.h>
#include <string.h>
#include <algorithm>

#define NV 4096
#define NPOOL 1024
#define NB 8
#define KNB 16
#define REMOVED 0xFFFFFFFFu
// bank-deconflicted histogram index: bin b -> word (b>>4) | ((b&15)<<6)
#define HIDX(b) ((((b) >> 4) | (((b) & 15) << 6)))

struct SIdx { unsigned short v[NPOOL]; };  // 2 KB by-value kernel arg

// ---------------- Threefry-2x32 (JAX-compatible, 20 rounds), host ----------
static inline void tf2x32_host(uint32_t k0, uint32_t k1,
                               uint32_t c0, uint32_t c1,
                               uint32_t& o0, uint32_t& o1) {
  uint32_t ks0 = k0, ks1 = k1, ks2 = k0 ^ k1 ^ 0x1BD11BDAu;
  uint32_t x0 = c0 + ks0, x1 = c1 + ks1;
#define TFR(r) { x0 += x1; x1 = (x1 << (r)) | (x1 >> (32 - (r))); x1 ^= x0; }
  TFR(13) TFR(15) TFR(26) TFR(6)
  x0 += ks1; x1 += ks2 + 1u;
  TFR(17) TFR(29) TFR(16) TFR(24)
  x0 += ks2; x1 += ks0 + 2u;
  TFR(13) TFR(15) TFR(26) TFR(6)
  x0 += ks0; x1 += ks1 + 3u;
  TFR(17) TFR(29) TFR(16) TFR(24)
  x0 += ks1; x1 += ks2 + 4u;
  TFR(13) TFR(15) TFR(26) TFR(6)
  x0 += ks2; x1 += ks0 + 5u;
#undef TFR
  o0 = x0; o1 = x1;
}

// Host: replicate jax.random.permutation(key(42), 4096)[:1024]  (validated absmax=0)
static void compute_sample_idx(SIdx& out) {
  static_assert(sizeof(SIdx) == 2048, "kernarg size");
  uint64_t arr[NV];
  uint16_t x[NV], tmp[NV];
  for (int i = 0; i < NV; ++i) x[i] = (uint16_t)i;
  uint32_t kh = 0u, kl = 42u;
  for (int round = 0; round < 2; ++round) {
    uint32_t nkh, nkl, sh, sl, t0, t1;
    tf2x32_host(kh, kl, 0u, 0u, nkh, nkl);
    tf2x32_host(kh, kl, 0u, 1u, sh, sl);
    kh = nkh; kl = nkl;
    for (int i = 0; i < NV; ++i) {
      tf2x32_host(sh, sl, 0u, (uint32_t)i, t0, t1);
      arr[i] = ((uint64_t)(t0 ^ t1) << 32) | (uint32_t)i;
    }
    std::sort(arr, arr + NV);
    for (int i = 0; i < NV; ++i) tmp[i] = x[(uint32_t)(arr[i] & 0xffffffffu)];
    memcpy(x, tmp, sizeof(x));
  }
  for (int i = 0; i < NPOOL; ++i) out.v[i] = x[i];
}

// validated 16-round extraction fallback (rare), predicate bin <= TAUB
#define FALLBACK(D, TAUB, WIN)                                             \
  {                                                                        \
    uint32_t mask = 0;                                                     \
    for (int r = 0; r < KNB; ++r) {                                        \
      uint32_t bv = REMOVED, bm = 0xFFFFFFFFu;                             \
      _Pragma("unroll")                                                    \
      for (int t = 0; t < 16; ++t) {                                       \
        const uint32_t v = (((mask >> t) & 1u) || ((D[t] >> 22) > (TAUB))) \
                               ? REMOVED : D[t];                           \
        const uint32_t m = (uint32_t)((tid << 4) + t);                     \
        if (v < bv || (v == bv && m < bm)) { bv = v; bm = m; }             \
      }                                                                    \
      for (int off = 32; off > 0; off >>= 1) {                             \
        const uint32_t ov = (uint32_t)__shfl_down((int)bv, off);           \
        const uint32_t om = (uint32_t)__shfl_down((int)bm, off);           \
        if (ov < bv || (ov == bv && om < bm)) { bv = ov; bm = om; }        \
      }                                                                    \
      if (lane == 0) wmin[warp] = ((unsigned long long)bv << 32) | bm;     \
      __syncthreads();                                                     \
      const unsigned long long p0 = wmin[0], p1 = wmin[1];                 \
      const unsigned long long p2 = wmin[2], p3 = wmin[3];                 \
      const unsigned long long pa = (p0 < p1) ? p0 : p1;                   \
      const unsigned long long pb = (p2 < p3) ? p2 : p3;                   \
      const int w = (int)(((pa < pb) ? pa : pb) & 0xFFFFFFFFu);            \
      if (tid == 0) (WIN)[r] = w;                                          \
      if (tid == (w >> 4)) mask |= 1u << (w & 15);                         \
      __syncthreads();                                                     \
    }                                                                      \
  }

// ---------------- K1: 256 threads / 2 queries (same batch). Shared vertex
// registers, dual minima-histogram selection on parallel warps, gather split
// across all 4 warps (warps 0,2 -> q0; 1,3 -> q1) with LDS fmax combine.
__global__ __launch_bounds__(256) void knn_pool_kernel(
    const float* __restrict__ vertices, const float* __restrict__ fm,
    const SIdx sidx,
    float* __restrict__ outV, float* __restrict__ outF) {
  __shared__ __attribute__((aligned(16))) uint32_t hist0[1024];
  __shared__ uint32_t hist1[1024];
  __shared__ unsigned long long cand0[64], cand1[64];
  __shared__ unsigned long long wmin[4];
  __shared__ int winners0[KNB], winners1[KNB];
  __shared__ int s_nc0, s_nc1, s_tb0, s_tb1;

  const int tid = threadIdx.x;
  const int lane = tid & 63;
  const int warp = tid >> 6;
  const int blk = blockIdx.x;      // 0..4095
  const int b = blk & 7;           // XCD-aware: batch b -> XCD b (bijective)
  const int i0 = (blk >> 3) << 1;
  const int i1 = i0 | 1;
  const int n0 = (int)sidx.v[i0];
  const int n1 = (int)sidx.v[i1];

  const float* vb = vertices + (size_t)b * NV * 3;
  const float q0x = vb[n0 * 3 + 0], q0y = vb[n0 * 3 + 1], q0z = vb[n0 * 3 + 2];
  const float q1x = vb[n1 * 3 + 0], q1y = vb[n1 * 3 + 1], q1z = vb[n1 * 3 + 2];
  // quadratic[n]: plain mul/add (XLA reduce of squares) — validated arithmetic
  const float qn0 = __fadd_rn(__fadd_rn(__fmul_rn(q0x, q0x), __fmul_rn(q0y, q0y)),
                              __fmul_rn(q0z, q0z));
  const float qn1 = __fadd_rn(__fadd_rn(__fmul_rn(q1x, q1x), __fmul_rn(q1y, q1y)),
                              __fmul_rn(q1z, q1z));

  // 12 independent float4 loads: this thread's 16 vertices, 192 B contiguous
  const float4* vb4 = (const float4*)vb + tid * 12;
  float f[48];
#pragma unroll
  for (int j = 0; j < 12; ++j) {
    const float4 v4 = vb4[j];
    f[4 * j + 0] = v4.x; f[4 * j + 1] = v4.y;
    f[4 * j + 2] = v4.z; f[4 * j + 3] = v4.w;
  }

  uint32_t d0[16], d1[16];
#pragma unroll
  for (int t = 0; t < 16; ++t) {
    const int m = (tid << 4) + t;
    const float cx = f[3 * t + 0], cy = f[3 * t + 1], cz = f[3 * t + 2];
    const float qm = __fadd_rn(__fadd_rn(__fmul_rn(cx, cx), __fmul_rn(cy, cy)),
                               __fmul_rn(cz, cz));  // shared between queries
    const float in0 = __fmaf_rn(cz, q0z, __fmaf_rn(cy, q0y, __fmul_rn(cx, q0x)));
    const float in1 = __fmaf_rn(cz, q1z, __fmaf_rn(cy, q1y, __fmul_rn(cx, q1x)));
    const float ds0 = __fadd_rn(__fadd_rn(__fmul_rn(-2.0f, in0), qm), qn0);
    const float ds1 = __fadd_rn(__fadd_rn(__fmul_rn(-2.0f, in1), qm), qn1);
    d0[t] = (m == n0) ? REMOVED : __float_as_uint(ds0);  // validated uint order
    d1[t] = (m == n1) ? REMOVED : __float_as_uint(ds1);
  }

  // per-thread minima
  uint32_t mn0 = d0[0], mn1 = d1[0];
#pragma unroll
  for (int t = 1; t < 16; ++t) {
    mn0 = (d0[t] < mn0) ? d0[t] : mn0;
    mn1 = (d1[t] < mn1) ? d1[t] : mn1;
  }

  const uint4 z4 = make_uint4(0, 0, 0, 0);
  ((uint4*)hist0)[tid] = z4;   // 256 * 16B = 4 KB each
  ((uint4*)hist1)[tid] = z4;
  if (tid == 0) { s_nc0 = 0; s_nc1 = 0; }
  __syncthreads();

  // minima histograms: 2 atomics/thread
  atomicAdd(&hist0[HIDX(mn0 >> 22)], 1u);
  atomicAdd(&hist1[HIDX(mn1 >> 22)], 1u);
  __syncthreads();

  // parallel scans: warp0 -> hist0 -> s_tb0 ; warp1 -> hist1 -> s_tb1
  if (warp < 2) {
    uint32_t* H = (warp == 0) ? hist0 : hist1;   // wave-uniform
    uint32_t s = 0;
#pragma unroll
    for (int j = 0; j < 16; ++j) s += H[j * 64 + lane];  // HIDX(lane*16+j)
    uint32_t inc = s;
    for (int off = 1; off < 64; off <<= 1) {
      const uint32_t o = (uint32_t)__shfl_up((int)inc, off);
      if (lane >= off) inc += o;
    }
    const uint32_t pre = inc - s;
    const bool cross = (pre < KNB) && (inc >= KNB);
    const unsigned long long bal = __ballot(cross);
    const int leader = __ffsll((unsigned long long)bal) - 1;
    if (lane == leader) {
      uint32_t c = pre;
      int tb = lane * 16 + 15;
      for (int j = 0; j < 16; ++j) {
        const uint32_t h = H[j * 64 + lane];
        if (c + h >= KNB) { tb = lane * 16 + j; break; }
        c += h;
      }
      if (warp == 0) s_tb0 = tb; else s_tb1 = tb;
    }
  }
  __syncthreads();

  const uint32_t taub0 = (uint32_t)s_tb0;
  const uint32_t taub1 = (uint32_t)s_tb1;

  // append candidates with bin <= taub (superset of exact top-16; C >= 16)
#pragma unroll
  for (int t = 0; t < 16; ++t) {
    const uint32_t v0 = d0[t];
    if ((v0 >> 22) <= taub0) {
      const int s = atomicAdd(&s_nc0, 1);
      if (s < 64)
        cand0[s] = ((unsigned long long)v0 << 32) | (uint32_t)((tid << 4) + t);
    }
    const uint32_t v1 = d1[t];
    if ((v1 >> 22) <= taub1) {
      const int s = atomicAdd(&s_nc1, 1);
      if (s < 64)
        cand1[s] = ((unsigned long long)v1 << 32) | (uint32_t)((tid << 4) + t);
    }
  }
  __syncthreads();

  const int C0 = s_nc0, C1 = s_nc1;
  // per-lane rank selection on parallel warps (exact top-16 by (dist,idx) u64)
  if (warp == 0 && C0 <= 64) {
    const unsigned long long me =
        (lane < C0) ? cand0[lane] : 0xFFFFFFFFFFFFFFFFull;
    int rank = 0;
    for (int j = 0; j < C0; ++j) rank += (cand0[j] < me) ? 1 : 0;
    if (lane < C0 && rank < KNB) winners0[rank] = (int)(me & 0xFFFFFFFFu);
  }
  if (warp == 1 && C1 <= 64) {
    const unsigned long long me =
        (lane < C1) ? cand1[lane] : 0xFFFFFFFFFFFFFFFFull;
    int rank = 0;
    for (int j = 0; j < C1; ++j) rank += (cand1[j] < me) ? 1 : 0;
    if (lane < C1 && rank < KNB) winners1[rank] = (int)(me & 0xFFFFFFFFu);
  }
  __syncthreads();

  // rare fallbacks (block-uniform conditions, barriers inside)
  if (C0 > 64) FALLBACK(d0, taub0, winners0);
  if (C1 > 64) FALLBACK(d1, taub1, winners1);

  // gather + max, split across all 4 warps: warps 0,2 -> q0; warps 1,3 -> q1.
  // Each warp does 8 rows; partials combined via LDS (alias dead hist0 area).
  // fmax split is exact (associative/commutative max over a fixed set).
  const float* fmb = fm + (size_t)b * NV * 256;
  {
    const int* W = ((warp & 1) == 0) ? winners0 : winners1;
    const int base = (warp >> 1) * 8;
    float4 acc = make_float4(-INFINITY, -INFINITY, -INFINITY, -INFINITY);
#pragma unroll
    for (int s = 0; s < 8; ++s) {
      const float4 v = ((const float4*)(fmb + (size_t)W[base + s] * 256))[lane];
      acc.x = fmaxf(acc.x, v.x); acc.y = fmaxf(acc.y, v.y);
      acc.z = fmaxf(acc.z, v.z); acc.w = fmaxf(acc.w, v.w);
    }
    float4* part = (float4*)hist0;        // 128 * 16 B = 2 KB, hist0 is dead
    if (warp >= 2) part[((warp & 1) << 6) + lane] = acc;
    __syncthreads();
    if (warp < 2) {
      const float4 o = part[((warp & 1) << 6) + lane];
      acc.x = fmaxf(acc.x, o.x); acc.y = fmaxf(acc.y, o.y);
      acc.z = fmaxf(acc.z, o.z); acc.w = fmaxf(acc.w, o.w);
      const int ii = (warp == 0) ? i0 : i1;
      ((float4*)(outF + ((size_t)b * NPOOL + ii) * 256))[lane] = acc;
    }
    if (warp == 2 && lane < 3) outV[((size_t)b * NPOOL + i0) * 3 + lane] = vb[n0 * 3 + lane];
    if (warp == 3 && lane < 3) outV[((size_t)b * NPOOL + i1) * 3 + lane] = vb[n1 * 3 + lane];
  }
}

extern "C" void kernel_launch(void* const* d_in, const int* in_sizes, int n_in,
                              void* d_out, int out_size, void* d_ws, size_t ws_size,
                              hipStream_t stream) {
  const float* vertices = (const float*)d_in[0];
  const float* fm = (const float*)d_in[1];
  float* out = (float*)d_out;
  float* outV = out;                      // (8, 1024, 3)
  float* outF = out + NB * NPOOL * 3;     // (8, 1024, 256)

  SIdx sidx;
  compute_sample_idx(sidx);               // pure host constant of key(42)

  knn_pool_kernel<<<NB * NPOOL / 2, 256, 0, stream>>>(vertices, fm, sidx, outV, outF);
}